// Round 1
// baseline (763.630 us; speedup 1.0000x reference)
//
#include <hip/hip_runtime.h>
#include <hip/hip_bf16.h>
#include <math.h>

#define T_DIM 1024
#define B_DIM 32
#define DIMF 512
#define DIMH 512
#define DIMS 1024
#define DIMW 512

#define BM 64
#define BN 64
#define BK 16

// ---------------- G = F @ Uw  (1024x512 @ 512x512) ----------------
// grid (T/16, DIMW/256), block 256
__global__ void k_G(const float* __restrict__ F, const float* __restrict__ Uw,
                    float* __restrict__ G) {
    __shared__ float Fs[16][DIMF];   // 32 KB
    const int r0 = blockIdx.x * 16;
    const int c  = blockIdx.y * 256 + threadIdx.x;
    const float4* Fv  = (const float4*)(F + (size_t)r0 * DIMF);
    float4* Fsv = (float4*)&Fs[0][0];
    for (int i = threadIdx.x; i < 16 * DIMF / 4; i += 256) Fsv[i] = Fv[i];
    __syncthreads();
    float acc[16];
#pragma unroll
    for (int r = 0; r < 16; ++r) acc[r] = 0.f;
    for (int k = 0; k < DIMF; ++k) {
        const float bv = Uw[(size_t)k * DIMW + c];
#pragma unroll
        for (int r = 0; r < 16; ++r) acc[r] = fmaf(Fs[r][k], bv, acc[r]);
    }
#pragma unroll
    for (int r = 0; r < 16; ++r) G[(size_t)(r0 + r) * DIMW + c] = acc[r];
}

// ---------------- SW[b,:] = s_prev[b,:] @ Ww + Vb ----------------
// grid (B), block 256 (each thread 2 cols: tid, tid+256)
__global__ void k_SW(const float* __restrict__ s_prev, const float* __restrict__ Ww,
                     const float* __restrict__ Vb, float* __restrict__ SW) {
    __shared__ float ss[DIMS];
    const int b = blockIdx.x;
    for (int i = threadIdx.x; i < DIMS / 4; i += 256)
        ((float4*)ss)[i] = ((const float4*)(s_prev + (size_t)b * DIMS))[i];
    __syncthreads();
    const int c0 = threadIdx.x, c1 = threadIdx.x + 256;
    float a0 = Vb[c0], a1 = Vb[c1];
    for (int k = 0; k < DIMS; ++k) {
        const float sv = ss[k];
        a0 = fmaf(sv, Ww[(size_t)k * DIMW + c0], a0);
        a1 = fmaf(sv, Ww[(size_t)k * DIMW + c1], a1);
    }
    SW[(size_t)b * DIMW + c0] = a0;
    SW[(size_t)b * DIMW + c1] = a1;
}

__global__ void k_zero(float* __restrict__ p, int n) {
    int i = blockIdx.x * 256 + threadIdx.x;
    if (i < n) p[i] = 0.f;
}

// ---------------- main fused GEMM ----------------
// z[b,t,w] = SW[b,w] + sum_c h[t,b,c]*Vw[c,w] + sum_k A2(b,t,k)*G[k,w]
//   A2(b,t,k) = a_prev[b, k+512-t] if 0<=k+512-t<1024 and t>0, else 0
// epilogue: e[b,t] += sum_w tanh(z)*ww[w]   (atomicAdd over w-tiles)
// grid (T/BM, DIMW/BN, B), block 256
__global__ void k_main(const float* __restrict__ h, const float* __restrict__ Vw,
                       const float* __restrict__ a_prev, const float* __restrict__ G,
                       const float* __restrict__ SW, const float* __restrict__ ww,
                       float* __restrict__ e) {
    __shared__ float As[BK][BM];   // A tile, transposed: As[k][t]
    __shared__ float Bs[BK][BN];
    const int t0  = blockIdx.x * BM;
    const int w0  = blockIdx.y * BN;
    const int b   = blockIdx.z;
    const int tid = threadIdx.x;
    const int tx  = tid & 15;      // col group
    const int ty  = tid >> 4;      // row group
    float acc[4][4] = {};

    // ---- part 1: hT[b] @ Vw,  K = DIMH ----
    for (int k0 = 0; k0 < DIMH; k0 += BK) {
        {
            const int r  = tid >> 2;         // 0..63
            const int kc = (tid & 3) * 4;    // 0,4,8,12
            const float4 v = *(const float4*)(h + ((size_t)(t0 + r) * B_DIM + b) * DIMH + k0 + kc);
            As[kc + 0][r] = v.x; As[kc + 1][r] = v.y;
            As[kc + 2][r] = v.z; As[kc + 3][r] = v.w;
            const int kr = tid >> 4;         // 0..15
            const int wc = (tid & 15) * 4;   // 0..60
            *(float4*)&Bs[kr][wc] = *(const float4*)(Vw + (size_t)(k0 + kr) * DIMW + w0 + wc);
        }
        __syncthreads();
#pragma unroll
        for (int kk = 0; kk < BK; ++kk) {
            const float4 av = *(const float4*)&As[kk][ty * 4];
            const float4 bv = *(const float4*)&Bs[kk][tx * 4];
            const float a4[4] = {av.x, av.y, av.z, av.w};
            const float b4[4] = {bv.x, bv.y, bv.z, bv.w};
#pragma unroll
            for (int i = 0; i < 4; ++i)
#pragma unroll
                for (int j = 0; j < 4; ++j)
                    acc[i][j] = fmaf(a4[i], b4[j], acc[i][j]);
        }
        __syncthreads();
    }

    // ---- part 2: Toeplitz(a_prev[b]) @ G ----
    const int kmin = max(0, t0 - 512);
    const int kmax = min(T_DIM - 1, t0 + BM - 1 + 511);
    for (int k0 = (kmin / BK) * BK; k0 <= kmax; k0 += BK) {
        {
            const int r  = tid >> 2;
            const int kc = (tid & 3) * 4;
            const int t  = t0 + r;
#pragma unroll
            for (int q = 0; q < 4; ++q) {
                const int k = k0 + kc + q;
                const int u = k + 512 - t;
                float v = 0.f;
                if (u >= 0 && u < T_DIM && t > 0) v = a_prev[(size_t)b * T_DIM + u];
                As[kc + q][r] = v;
            }
            const int kr = tid >> 4;
            const int wc = (tid & 15) * 4;
            *(float4*)&Bs[kr][wc] = *(const float4*)(G + (size_t)(k0 + kr) * DIMW + w0 + wc);
        }
        __syncthreads();
#pragma unroll
        for (int kk = 0; kk < BK; ++kk) {
            const float4 av = *(const float4*)&As[kk][ty * 4];
            const float4 bv = *(const float4*)&Bs[kk][tx * 4];
            const float a4[4] = {av.x, av.y, av.z, av.w};
            const float b4[4] = {bv.x, bv.y, bv.z, bv.w};
#pragma unroll
            for (int i = 0; i < 4; ++i)
#pragma unroll
                for (int j = 0; j < 4; ++j)
                    acc[i][j] = fmaf(a4[i], b4[j], acc[i][j]);
        }
        __syncthreads();
    }

    // ---- epilogue: tanh, dot with ww, reduce over tx, atomicAdd ----
#pragma unroll
    for (int i = 0; i < 4; ++i) {
        const int t = t0 + ty * 4 + i;
        float s = 0.f;
#pragma unroll
        for (int j = 0; j < 4; ++j) {
            const int w = w0 + tx * 4 + j;
            const float z = acc[i][j] + SW[(size_t)b * DIMW + w];
            s = fmaf(tanhf(z), ww[w], s);
        }
        s += __shfl_xor(s, 1, 64);
        s += __shfl_xor(s, 2, 64);
        s += __shfl_xor(s, 4, 64);
        s += __shfl_xor(s, 8, 64);
        if (tx == 0) atomicAdd(&e[(size_t)b * T_DIM + t], s);
    }
}

// ---------------- softmax over t per batch ----------------
__device__ __forceinline__ float decode_beta(const void* p) {
    const int iv = *(const int*)p;
    const float fv = __int_as_float(iv);
    const float afv = fabsf(fv);
    if (afv >= 1e-6f && afv <= 1e6f) return fv;   // plausible float encoding
    return (float)iv;                              // else it was an int
}

__global__ void k_softmax(const float* __restrict__ e, const void* __restrict__ beta_p,
                          float* __restrict__ out) {
    const int b = blockIdx.x;
    const float beta = decode_beta(beta_p);
    __shared__ float redm[4];
    __shared__ float reds[4];
    float v[4];
    float m = -INFINITY;
#pragma unroll
    for (int i = 0; i < 4; ++i) {
        v[i] = beta * e[(size_t)b * T_DIM + threadIdx.x * 4 + i];
        m = fmaxf(m, v[i]);
    }
    for (int off = 1; off < 64; off <<= 1) m = fmaxf(m, __shfl_xor(m, off, 64));
    const int wid = threadIdx.x >> 6, lane = threadIdx.x & 63;
    if (lane == 0) redm[wid] = m;
    __syncthreads();
    m = fmaxf(fmaxf(redm[0], redm[1]), fmaxf(redm[2], redm[3]));
    float s = 0.f;
    float ex[4];
#pragma unroll
    for (int i = 0; i < 4; ++i) { ex[i] = expf(v[i] - m); s += ex[i]; }
    for (int off = 1; off < 64; off <<= 1) s += __shfl_xor(s, off, 64);
    if (lane == 0) reds[wid] = s;
    __syncthreads();
    s = reds[0] + reds[1] + reds[2] + reds[3];
    const float inv = 1.f / s;
#pragma unroll
    for (int i = 0; i < 4; ++i)
        out[(size_t)b * T_DIM + threadIdx.x * 4 + i] = ex[i] * inv;
}

extern "C" void kernel_launch(void* const* d_in, const int* in_sizes, int n_in,
                              void* d_out, int out_size, void* d_ws, size_t ws_size,
                              hipStream_t stream) {
    const float* F      = (const float*)d_in[0];
    const float* a_prev = (const float*)d_in[1];
    const float* s_prev = (const float*)d_in[2];
    const float* h      = (const float*)d_in[3];
    const float* Ww     = (const float*)d_in[4];
    const float* Vw     = (const float*)d_in[5];
    const float* Vb     = (const float*)d_in[6];
    const float* Uw     = (const float*)d_in[7];
    const float* ww     = (const float*)d_in[8];
    const void*  beta_p = d_in[9];
    float* out = (float*)d_out;

    float* ws = (float*)d_ws;
    float* G  = ws;                         // 1024*512 = 524288 floats
    float* SW = ws + 524288;                // 32*512   = 16384 floats
    float* e  = ws + 524288 + 16384;        // 32*1024  = 32768 floats

    k_G      <<<dim3(64, 2),     256, 0, stream>>>(F, Uw, G);
    k_SW     <<<dim3(32),        256, 0, stream>>>(s_prev, Ww, Vb, SW);
    k_zero   <<<dim3(128),       256, 0, stream>>>(e, B_DIM * T_DIM);
    k_main   <<<dim3(16, 8, 32), 256, 0, stream>>>(h, Vw, a_prev, G, SW, ww, e);
    k_softmax<<<dim3(32),        256, 0, stream>>>(e, beta_p, out);
}

// Round 2
// 238.130 us; speedup vs baseline: 3.2068x; 3.2068x over previous
//
#include <hip/hip_runtime.h>
#include <hip/hip_bf16.h>
#include <math.h>

#define T_DIM 1024
#define B_DIM 32
#define DIMF 512
#define DIMH 512
#define DIMS 1024
#define DIMW 512

#define BM2 128
#define BN2 128
#define PITCH 40   // bf16 elems per LDS row (32 data + 8 pad) -> 80B pitch, 2-way banks (free)

typedef __attribute__((ext_vector_type(8))) short short8;
typedef __attribute__((ext_vector_type(4))) float f32x4;

__device__ __forceinline__ unsigned f2bf1(float x) {
    unsigned a = __float_as_uint(x);
    return (a + 0x7FFFu + ((a >> 16) & 1u)) >> 16;
}
__device__ __forceinline__ unsigned f2bf2(float lo, float hi) {
    return f2bf1(lo) | (f2bf1(hi) << 16);
}

// ---------------- GT[w][k] = bf16( (F @ Uw)^T ) ----------------
// grid (64, 2), block 256
__global__ void k_G_gt(const float* __restrict__ F, const float* __restrict__ Uw,
                       unsigned short* __restrict__ GT) {
    __shared__ float Fs[16][DIMF];   // 32 KB
    const int r0 = blockIdx.x * 16;
    const int c  = blockIdx.y * 256 + threadIdx.x;
    const float4* Fv  = (const float4*)(F + (size_t)r0 * DIMF);
    float4* Fsv = (float4*)&Fs[0][0];
    for (int i = threadIdx.x; i < 16 * DIMF / 4; i += 256) Fsv[i] = Fv[i];
    __syncthreads();
    float acc[16];
#pragma unroll
    for (int r = 0; r < 16; ++r) acc[r] = 0.f;
    for (int k = 0; k < DIMF; ++k) {
        const float bv = Uw[(size_t)k * DIMW + c];
#pragma unroll
        for (int r = 0; r < 16; ++r) acc[r] = fmaf(Fs[r][k], bv, acc[r]);
    }
    uint4 o0, o1;
    o0.x = f2bf2(acc[0], acc[1]);   o0.y = f2bf2(acc[2], acc[3]);
    o0.z = f2bf2(acc[4], acc[5]);   o0.w = f2bf2(acc[6], acc[7]);
    o1.x = f2bf2(acc[8], acc[9]);   o1.y = f2bf2(acc[10], acc[11]);
    o1.z = f2bf2(acc[12], acc[13]); o1.w = f2bf2(acc[14], acc[15]);
    *(uint4*)(GT + (size_t)c * T_DIM + r0)     = o0;
    *(uint4*)(GT + (size_t)c * T_DIM + r0 + 8) = o1;
}

// ---------------- SW[b,:] = s_prev[b,:] @ Ww + Vb (fp32) ----------------
__global__ void k_SW(const float* __restrict__ s_prev, const float* __restrict__ Ww,
                     const float* __restrict__ Vb, float* __restrict__ SW) {
    __shared__ float ss[DIMS];
    const int b = blockIdx.x;
    for (int i = threadIdx.x; i < DIMS / 4; i += 256)
        ((float4*)ss)[i] = ((const float4*)(s_prev + (size_t)b * DIMS))[i];
    __syncthreads();
    const int c0 = threadIdx.x, c1 = threadIdx.x + 256;
    float a0 = Vb[c0], a1 = Vb[c1];
    for (int k = 0; k < DIMS; ++k) {
        const float sv = ss[k];
        a0 = fmaf(sv, Ww[(size_t)k * DIMW + c0], a0);
        a1 = fmaf(sv, Ww[(size_t)k * DIMW + c1], a1);
    }
    SW[(size_t)b * DIMW + c0] = a0;
    SW[(size_t)b * DIMW + c1] = a1;
}

// ---------------- VwT[n][k] = bf16(Vw[k][n]) ----------------
// grid (16,16), block 256
__global__ void k_pack_vwT(const float* __restrict__ Vw, unsigned short* __restrict__ VwT) {
    __shared__ float t[32][33];
    const int k0 = blockIdx.x * 32, n0 = blockIdx.y * 32;
    const int x = threadIdx.x & 31, y = threadIdx.x >> 5;   // y: 0..7
#pragma unroll
    for (int i = 0; i < 4; ++i)
        t[y + 8 * i][x] = Vw[(size_t)(k0 + y + 8 * i) * DIMW + n0 + x];
    __syncthreads();
#pragma unroll
    for (int i = 0; i < 4; ++i)
        VwT[(size_t)(n0 + y + 8 * i) * DIMH + k0 + x] = (unsigned short)f2bf1(t[x][y + 8 * i]);
}

// ---------------- P[b][s][i] = bf16(a_logical[b][i+s]) ----------------
// a_logical[j] = a_prev[b][j-512] for j in [512,1536), else 0.  grid 256 (b*8+s), block 256
__global__ void k_pack_a(const float* __restrict__ a_prev, unsigned short* __restrict__ P) {
    const int bs = blockIdx.x;
    const int b = bs >> 3, s = bs & 7;
    for (int i = threadIdx.x; i < 2048; i += 256) {
        const int j = i + s;
        float v = 0.f;
        if (j >= 512 && j < 1536) v = a_prev[(size_t)b * T_DIM + j - 512];
        P[(size_t)bs * 2048 + i] = (unsigned short)f2bf1(v);
    }
}

__global__ void k_zero(float* __restrict__ p, int n) {
    int i = blockIdx.x * 256 + threadIdx.x;
    if (i < n) p[i] = 0.f;
}

// ---------------- main fused MFMA kernel ----------------
// grid (DIMW/BN2=4, T/BM2=8, B=32), block 256 (4 waves, 2x2)
__global__ void __launch_bounds__(256) k_main(
    const float* __restrict__ h, const unsigned short* __restrict__ VwT,
    const unsigned short* __restrict__ GT, const unsigned short* __restrict__ P,
    const float* __restrict__ SW, const float* __restrict__ ww,
    float* __restrict__ e) {
    __shared__ unsigned short As[BM2 * PITCH];
    __shared__ unsigned short Bs[BN2 * PITCH];
    const int w0 = blockIdx.x * BN2;
    const int t0 = blockIdx.y * BM2;
    const int b  = blockIdx.z;
    const int tid  = threadIdx.x;
    const int lane = tid & 63;
    const int wv   = tid >> 6;
    const int wm = wv >> 1, wn = wv & 1;
    const int g = lane >> 4, r16 = lane & 15;

    f32x4 acc[4][4];
#pragma unroll
    for (int m = 0; m < 4; ++m)
#pragma unroll
        for (int n = 0; n < 4; ++n) acc[m][n] = (f32x4)0.f;

    // staging thread mapping: half-row per thread
    const int tA = tid >> 1;             // 0..127
    const int cA = (tid & 1) * 16;       // 0 or 16 (bf16 elems)
    const float*          hsrc = h   + ((size_t)(t0 + tA) * B_DIM + b) * DIMH + cA;
    const unsigned short* vsrc = VwT + (size_t)(w0 + tA) * DIMH + cA;
    const unsigned short* gsrc = GT  + (size_t)(w0 + tA) * T_DIM + cA;
    unsigned short* AsW = &As[tA * PITCH + cA];
    unsigned short* BsW = &Bs[tA * PITCH + cA];

    // fragment read pointers
    const unsigned short* ApR = &As[(wm * 64 + r16) * PITCH + g * 8];
    const unsigned short* BpR = &Bs[(wn * 64 + r16) * PITCH + g * 8];

    // ================= part 1: h^T @ Vw =================
    for (int k0 = 0; k0 < DIMH; k0 += 32) {
        const float4 f0 = *(const float4*)(hsrc + k0);
        const float4 f1 = *(const float4*)(hsrc + k0 + 4);
        const float4 f2 = *(const float4*)(hsrc + k0 + 8);
        const float4 f3 = *(const float4*)(hsrc + k0 + 12);
        const uint4  v0 = *(const uint4*)(vsrc + k0);
        const uint4  v1 = *(const uint4*)(vsrc + k0 + 8);
        uint4 o0, o1;
        o0.x = f2bf2(f0.x, f0.y); o0.y = f2bf2(f0.z, f0.w);
        o0.z = f2bf2(f1.x, f1.y); o0.w = f2bf2(f1.z, f1.w);
        o1.x = f2bf2(f2.x, f2.y); o1.y = f2bf2(f2.z, f2.w);
        o1.z = f2bf2(f3.x, f3.y); o1.w = f2bf2(f3.z, f3.w);
        __syncthreads();                 // previous compute done
        *(uint4*)(AsW)     = o0;
        *(uint4*)(AsW + 8) = o1;
        *(uint4*)(BsW)     = v0;
        *(uint4*)(BsW + 8) = v1;
        __syncthreads();                 // staging visible
        short8 af[4], bfv[4];
#pragma unroll
        for (int m = 0; m < 4; ++m) af[m]  = *(const short8*)(ApR + m * 16 * PITCH);
#pragma unroll
        for (int n = 0; n < 4; ++n) bfv[n] = *(const short8*)(BpR + n * 16 * PITCH);
#pragma unroll
        for (int m = 0; m < 4; ++m)
#pragma unroll
            for (int n = 0; n < 4; ++n)
                acc[m][n] = __builtin_amdgcn_mfma_f32_16x16x32_bf16(af[m], bfv[n], acc[m][n], 0, 0, 0);
    }

    // ================= part 2: Toeplitz(a) @ G =================
    const int kstart = max(0, t0 - 512);
    const int kend   = min(T_DIM - 1, t0 + BM2 - 1 + 511);
    const unsigned short* Pb = P + (size_t)b * 8 * 2048;

    for (int k0 = kstart; k0 <= kend; k0 += 32) {
        const uint4 v0 = *(const uint4*)(gsrc + k0);
        const uint4 v1 = *(const uint4*)(gsrc + k0 + 8);
        short8 af[4];
#pragma unroll
        for (int m = 0; m < 4; ++m) {
            const int trow = t0 + wm * 64 + m * 16 + r16;
            const int j0 = k0 + g * 8 + 1024 - trow;   // in [1, 2040]
            const int s = j0 & 7;
            short8 raw = *(const short8*)(Pb + s * 2048 + (j0 - s));
            if (trow == 0) raw = (short8)(short)0;     // f row 0 is zero
            af[m] = raw;
        }
        __syncthreads();
        *(uint4*)(BsW)     = v0;
        *(uint4*)(BsW + 8) = v1;
        __syncthreads();
        short8 bfv[4];
#pragma unroll
        for (int n = 0; n < 4; ++n) bfv[n] = *(const short8*)(BpR + n * 16 * PITCH);
#pragma unroll
        for (int m = 0; m < 4; ++m)
#pragma unroll
            for (int n = 0; n < 4; ++n)
                acc[m][n] = __builtin_amdgcn_mfma_f32_16x16x32_bf16(af[m], bfv[n], acc[m][n], 0, 0, 0);
    }

    // ================= epilogue: tanh, dot ww, reduce, atomicAdd =================
    float swv[4], wwv[4];
#pragma unroll
    for (int n = 0; n < 4; ++n) {
        const int w = w0 + wn * 64 + n * 16 + r16;
        swv[n] = SW[(size_t)b * DIMW + w];
        wwv[n] = ww[w];
    }
#pragma unroll
    for (int m = 0; m < 4; ++m) {
#pragma unroll
        for (int reg = 0; reg < 4; ++reg) {
            float s = 0.f;
#pragma unroll
            for (int n = 0; n < 4; ++n)
                s = fmaf(tanhf(acc[m][n][reg] + swv[n]), wwv[n], s);
            s += __shfl_xor(s, 1, 64);
            s += __shfl_xor(s, 2, 64);
            s += __shfl_xor(s, 4, 64);
            s += __shfl_xor(s, 8, 64);
            if (r16 == 0) {
                const int trow = t0 + wm * 64 + m * 16 + g * 4 + reg;
                atomicAdd(&e[(size_t)b * T_DIM + trow], s);
            }
        }
    }
}

// ---------------- softmax over t per batch ----------------
__device__ __forceinline__ float decode_beta(const void* p) {
    const int iv = *(const int*)p;
    const float fv = __int_as_float(iv);
    const float afv = fabsf(fv);
    if (afv >= 1e-6f && afv <= 1e6f) return fv;
    return (float)iv;
}

__global__ void k_softmax(const float* __restrict__ e, const void* __restrict__ beta_p,
                          float* __restrict__ out) {
    const int b = blockIdx.x;
    const float beta = decode_beta(beta_p);
    __shared__ float redm[4];
    __shared__ float reds[4];
    float v[4];
    float m = -INFINITY;
#pragma unroll
    for (int i = 0; i < 4; ++i) {
        v[i] = beta * e[(size_t)b * T_DIM + threadIdx.x * 4 + i];
        m = fmaxf(m, v[i]);
    }
    for (int off = 1; off < 64; off <<= 1) m = fmaxf(m, __shfl_xor(m, off, 64));
    const int wid = threadIdx.x >> 6, lane = threadIdx.x & 63;
    if (lane == 0) redm[wid] = m;
    __syncthreads();
    m = fmaxf(fmaxf(redm[0], redm[1]), fmaxf(redm[2], redm[3]));
    float s = 0.f;
    float ex[4];
#pragma unroll
    for (int i = 0; i < 4; ++i) { ex[i] = expf(v[i] - m); s += ex[i]; }
    for (int off = 1; off < 64; off <<= 1) s += __shfl_xor(s, off, 64);
    if (lane == 0) reds[wid] = s;
    __syncthreads();
    s = reds[0] + reds[1] + reds[2] + reds[3];
    const float inv = 1.f / s;
#pragma unroll
    for (int i = 0; i < 4; ++i)
        out[(size_t)b * T_DIM + threadIdx.x * 4 + i] = ex[i] * inv;
}

extern "C" void kernel_launch(void* const* d_in, const int* in_sizes, int n_in,
                              void* d_out, int out_size, void* d_ws, size_t ws_size,
                              hipStream_t stream) {
    const float* F      = (const float*)d_in[0];
    const float* a_prev = (const float*)d_in[1];
    const float* s_prev = (const float*)d_in[2];
    const float* h      = (const float*)d_in[3];
    const float* Ww     = (const float*)d_in[4];
    const float* Vw     = (const float*)d_in[5];
    const float* Vb     = (const float*)d_in[6];
    const float* Uw     = (const float*)d_in[7];
    const float* ww     = (const float*)d_in[8];
    const void*  beta_p = d_in[9];
    float* out = (float*)d_out;

    char* ws = (char*)d_ws;
    unsigned short* GT  = (unsigned short*)(ws);                       // 1 MB
    unsigned short* VwT = (unsigned short*)(ws + (1u << 20));          // 512 KB
    unsigned short* P   = (unsigned short*)(ws + (1u << 20) + (512u << 10));          // 1 MB
    float* SW = (float*)(ws + (2u << 20) + (512u << 10));              // 64 KB
    float* e  = (float*)(ws + (2u << 20) + (512u << 10) + (64u << 10)); // 128 KB

    k_G_gt    <<<dim3(64, 2),    256, 0, stream>>>(F, Uw, GT);
    k_SW      <<<dim3(32),       256, 0, stream>>>(s_prev, Ww, Vb, SW);
    k_pack_vwT<<<dim3(16, 16),   256, 0, stream>>>(Vw, VwT);
    k_pack_a  <<<dim3(256),      256, 0, stream>>>(a_prev, P);
    k_zero    <<<dim3(128),      256, 0, stream>>>(e, B_DIM * T_DIM);
    k_main    <<<dim3(4, 8, 32), 256, 0, stream>>>(h, VwT, GT, P, SW, ww, e);
    k_softmax <<<dim3(32),       256, 0, stream>>>(e, beta_p, out);
}